// Round 1
// baseline (496.465 us; speedup 1.0000x reference)
//
#include <hip/hip_runtime.h>

#define F_IN 128
#define HC1 256   // HEADS*HID
#define HID 32
#define HEADS 8

__device__ __forceinline__ float lrelu(float x){ return x > 0.f ? x : 0.2f*x; }

// ---------------- CSR build ----------------
__global__ void k_deg(const int* __restrict__ dst, int* __restrict__ deg, int E){
  int t = blockIdx.x*blockDim.x + threadIdx.x;
  if (t < E) atomicAdd(&deg[dst[t]], 1);
}

__global__ __launch_bounds__(1024) void k_scan(const int* __restrict__ deg, int* __restrict__ offs,
                                               int N, int E){
  __shared__ int part[1024];
  int t = threadIdx.x;
  int C = (N + 1023) >> 10;
  int lo = t*C, hi = min(lo + C, N);
  int s = 0;
  for (int i = lo; i < hi; ++i) s += deg[i];
  part[t] = s;
  __syncthreads();
  for (int off = 1; off < 1024; off <<= 1){
    int v = (t >= off) ? part[t - off] : 0;
    __syncthreads();
    part[t] += v;
    __syncthreads();
  }
  int base = (t == 0) ? 0 : part[t-1];
  for (int i = lo; i < hi; ++i){ offs[i] = base; base += deg[i]; }
  if (t == 0) offs[N] = E;
}

__global__ void k_scatter(const int* __restrict__ src, const int* __restrict__ dst,
                          const int* __restrict__ offs, int* __restrict__ cur,
                          int* __restrict__ csr, int E){
  int t = blockIdx.x*blockDim.x + threadIdx.x;
  if (t < E){
    int d = dst[t];
    int p = offs[d] + atomicAdd(&cur[d], 1);
    csr[p] = src[t];
  }
}

// ---------------- GEMM1: x[M,128] @ W1[128,256] -> h1[M,256] ----------------
__global__ __launch_bounds__(256) void k_gemm1(const float* __restrict__ A, const float* __restrict__ B,
                                               float* __restrict__ C, int M){
  __shared__ float As[64][68];   // [k][m]
  __shared__ float Bs[64][68];   // [k][n]
  int tid = threadIdx.x;
  int m0 = (tid >> 4) << 2;
  int n0 = (tid & 15) << 2;
  int rowbase = blockIdx.x * 64;
  int colbase = blockIdx.y * 64;
  float acc[4][4] = {};
  for (int k0 = 0; k0 < F_IN; k0 += 64){
    #pragma unroll
    for (int j = 0; j < 4; ++j){
      int q = tid + 256*j;
      int r = q >> 4;            // 0..63
      int kk = (q & 15) << 2;    // 0..60
      int row = rowbase + r;
      float4 va = make_float4(0.f,0.f,0.f,0.f);
      if (row < M) va = *(const float4*)(A + (size_t)row*F_IN + k0 + kk);
      As[kk+0][r] = va.x; As[kk+1][r] = va.y; As[kk+2][r] = va.z; As[kk+3][r] = va.w;
      float4 vb = *(const float4*)(B + (size_t)(k0 + r)*HC1 + colbase + kk);
      *(float4*)&Bs[r][kk] = vb;
    }
    __syncthreads();
    #pragma unroll
    for (int k = 0; k < 64; ++k){
      float4 a = *(const float4*)&As[k][m0];
      float4 b = *(const float4*)&Bs[k][n0];
      acc[0][0] += a.x*b.x; acc[0][1] += a.x*b.y; acc[0][2] += a.x*b.z; acc[0][3] += a.x*b.w;
      acc[1][0] += a.y*b.x; acc[1][1] += a.y*b.y; acc[1][2] += a.y*b.z; acc[1][3] += a.y*b.w;
      acc[2][0] += a.z*b.x; acc[2][1] += a.z*b.y; acc[2][2] += a.z*b.z; acc[2][3] += a.z*b.w;
      acc[3][0] += a.w*b.x; acc[3][1] += a.w*b.y; acc[3][2] += a.w*b.z; acc[3][3] += a.w*b.w;
    }
    __syncthreads();
  }
  #pragma unroll
  for (int i = 0; i < 4; ++i){
    int row = rowbase + m0 + i;
    if (row < M)
      *(float4*)(C + (size_t)row*HC1 + colbase + n0) =
        make_float4(acc[i][0], acc[i][1], acc[i][2], acc[i][3]);
  }
}

// ---------------- GEMM2: h2[M,256] @ W2[256,32] -> g2[M,32] ----------------
__global__ __launch_bounds__(256) void k_gemm2(const float* __restrict__ A, const float* __restrict__ B,
                                               float* __restrict__ C, int M){
  __shared__ float As[64][132];  // [k][m], m-tile 128
  __shared__ float Bs[64][36];   // [k][n]
  int tid = threadIdx.x;
  int m0 = (tid >> 3) << 2;   // 0..124
  int n0 = (tid & 7) << 2;    // 0..28
  int rowbase = blockIdx.x * 128;
  float acc[4][4] = {};
  for (int k0 = 0; k0 < HC1; k0 += 64){
    #pragma unroll
    for (int j = 0; j < 8; ++j){
      int q = tid + 256*j;       // 0..2047
      int r = q >> 4;            // 0..127
      int kk = (q & 15) << 2;    // 0..60
      int row = rowbase + r;
      float4 va = make_float4(0.f,0.f,0.f,0.f);
      if (row < M) va = *(const float4*)(A + (size_t)row*HC1 + k0 + kk);
      As[kk+0][r] = va.x; As[kk+1][r] = va.y; As[kk+2][r] = va.z; As[kk+3][r] = va.w;
    }
    #pragma unroll
    for (int j = 0; j < 2; ++j){
      int q = tid + 256*j;    // 0..511
      int r = q >> 3;         // 0..63
      int nn = (q & 7) << 2;  // 0..28
      *(float4*)&Bs[r][nn] = *(const float4*)(B + (size_t)(k0 + r)*HID + nn);
    }
    __syncthreads();
    #pragma unroll
    for (int k = 0; k < 64; ++k){
      float4 a = *(const float4*)&As[k][m0];
      float4 b = *(const float4*)&Bs[k][n0];
      acc[0][0] += a.x*b.x; acc[0][1] += a.x*b.y; acc[0][2] += a.x*b.z; acc[0][3] += a.x*b.w;
      acc[1][0] += a.y*b.x; acc[1][1] += a.y*b.y; acc[1][2] += a.y*b.z; acc[1][3] += a.y*b.w;
      acc[2][0] += a.z*b.x; acc[2][1] += a.z*b.y; acc[2][2] += a.z*b.z; acc[2][3] += a.z*b.w;
      acc[3][0] += a.w*b.x; acc[3][1] += a.w*b.y; acc[3][2] += a.w*b.z; acc[3][3] += a.w*b.w;
    }
    __syncthreads();
  }
  #pragma unroll
  for (int i = 0; i < 4; ++i){
    int row = rowbase + m0 + i;
    if (row < M)
      *(float4*)(C + (size_t)row*HID + n0) =
        make_float4(acc[i][0], acc[i][1], acc[i][2], acc[i][3]);
  }
}

// ---------------- per-node alpha dots ----------------
__global__ void k_alpha1(const float* __restrict__ h1, const float* __restrict__ a_src,
                         const float* __restrict__ a_dst, float* __restrict__ os,
                         float* __restrict__ od, int NH){
  int t = blockIdx.x*blockDim.x + threadIdx.x;
  if (t >= NH) return;
  int h = t & 7;
  const float4* hp = (const float4*)(h1 + (size_t)t*HID);
  const float4* sp = (const float4*)(a_src + h*HID);
  const float4* dp = (const float4*)(a_dst + h*HID);
  float ss = 0.f, dd = 0.f;
  #pragma unroll
  for (int j = 0; j < 8; ++j){
    float4 v = hp[j], s = sp[j], d = dp[j];
    ss += v.x*s.x + v.y*s.y + v.z*s.z + v.w*s.w;
    dd += v.x*d.x + v.y*d.y + v.z*d.z + v.w*d.w;
  }
  os[t] = ss; od[t] = dd;
}

__global__ void k_alpha2(const float* __restrict__ g2, const float* __restrict__ a_src,
                         const float* __restrict__ a_dst, float* __restrict__ os,
                         float* __restrict__ od, int N){
  int t = blockIdx.x*blockDim.x + threadIdx.x;
  if (t >= N) return;
  const float4* hp = (const float4*)(g2 + (size_t)t*HID);
  const float4* sp = (const float4*)a_src;
  const float4* dp = (const float4*)a_dst;
  float ss = 0.f, dd = 0.f;
  #pragma unroll
  for (int j = 0; j < 8; ++j){
    float4 v = hp[j], s = sp[j], d = dp[j];
    ss += v.x*s.x + v.y*s.y + v.z*s.z + v.w*s.w;
    dd += v.x*d.x + v.y*d.y + v.z*d.z + v.w*d.w;
  }
  os[t] = ss; od[t] = dd;
}

// ---------------- layer-1 aggregation: wave per node, online softmax ----------------
__global__ __launch_bounds__(256) void k_agg1(const float* __restrict__ h1,
    const float* __restrict__ as1, const float* __restrict__ ad1,
    const int* __restrict__ offs, const int* __restrict__ csr,
    const float* __restrict__ b1, float* __restrict__ h2, int N){
  int w = (blockIdx.x*blockDim.x + threadIdx.x) >> 6;
  if (w >= N) return;
  int lane = threadIdx.x & 63;
  int c0 = lane << 2;        // 0..252
  int h = lane >> 3;         // 0..7
  int n = w;
  float adv = ad1[n*HEADS + h];
  // implicit self-loop (src = n)
  float m = lrelu(as1[n*HEADS + h] + adv);
  float l = 1.f;
  float4 acc = *(const float4*)(h1 + (size_t)n*HC1 + c0);
  int s0 = offs[n], s1 = offs[n+1];
  for (int i = s0; i < s1; ++i){
    int s = csr[i];
    float e = lrelu(as1[s*HEADS + h] + adv);
    float4 v = *(const float4*)(h1 + (size_t)s*HC1 + c0);
    float mn = fmaxf(m, e);
    float sc = __expf(m - mn);
    float p  = __expf(e - mn);
    l = l*sc + p;
    acc.x = acc.x*sc + p*v.x;
    acc.y = acc.y*sc + p*v.y;
    acc.z = acc.z*sc + p*v.z;
    acc.w = acc.w*sc + p*v.w;
    m = mn;
  }
  float rl = 1.f / l;
  float4 bb = *(const float4*)(b1 + c0);
  float4 o;
  o.x = acc.x*rl + bb.x; o.y = acc.y*rl + bb.y;
  o.z = acc.z*rl + bb.z; o.w = acc.w*rl + bb.w;
  o.x = o.x > 0.f ? o.x : __expf(o.x) - 1.f;
  o.y = o.y > 0.f ? o.y : __expf(o.y) - 1.f;
  o.z = o.z > 0.f ? o.z : __expf(o.z) - 1.f;
  o.w = o.w > 0.f ? o.w : __expf(o.w) - 1.f;
  *(float4*)(h2 + (size_t)n*HC1 + c0) = o;
}

// ---------------- layer-2 aggregation: wave per node, 8 edge-groups ----------------
__global__ __launch_bounds__(256) void k_agg2(const float* __restrict__ g2,
    const float* __restrict__ as2, const float* __restrict__ ad2,
    const int* __restrict__ offs, const int* __restrict__ csr,
    const float* __restrict__ b2, float* __restrict__ out, int N){
  int w = (blockIdx.x*blockDim.x + threadIdx.x) >> 6;
  if (w >= N) return;
  int lane = threadIdx.x & 63;
  int g = lane >> 3;          // edge group 0..7
  int c0 = (lane & 7) << 2;   // 0..28
  int n = w;
  float adv = ad2[n];
  float m = -1e30f, l = 0.f;
  float4 acc = make_float4(0.f,0.f,0.f,0.f);
  if (g == 0){
    m = lrelu(as2[n] + adv);
    l = 1.f;
    acc = *(const float4*)(g2 + (size_t)n*HID + c0);
  }
  int s0 = offs[n], s1 = offs[n+1];
  for (int i = s0 + g; i < s1; i += 8){
    int s = csr[i];
    float e = lrelu(as2[s] + adv);
    float4 v = *(const float4*)(g2 + (size_t)s*HID + c0);
    float mn = fmaxf(m, e);
    float sc = __expf(m - mn);
    float p  = __expf(e - mn);
    l = l*sc + p;
    acc.x = acc.x*sc + p*v.x;
    acc.y = acc.y*sc + p*v.y;
    acc.z = acc.z*sc + p*v.z;
    acc.w = acc.w*sc + p*v.w;
    m = mn;
  }
  #pragma unroll
  for (int mask = 8; mask <= 32; mask <<= 1){
    float mo = __shfl_xor(m, mask, 64);
    float lo = __shfl_xor(l, mask, 64);
    float ax = __shfl_xor(acc.x, mask, 64);
    float ay = __shfl_xor(acc.y, mask, 64);
    float az = __shfl_xor(acc.z, mask, 64);
    float aw = __shfl_xor(acc.w, mask, 64);
    float mn = fmaxf(m, mo);
    float sc = __expf(m - mn), so = __expf(mo - mn);
    l = l*sc + lo*so;
    acc.x = acc.x*sc + ax*so;
    acc.y = acc.y*sc + ay*so;
    acc.z = acc.z*sc + az*so;
    acc.w = acc.w*sc + aw*so;
    m = mn;
  }
  if (g == 0){
    float rl = 1.f/l;
    float4 bb = *(const float4*)(b2 + c0);
    *(float4*)(out + (size_t)n*HID + c0) =
      make_float4(acc.x*rl + bb.x, acc.y*rl + bb.y, acc.z*rl + bb.z, acc.w*rl + bb.w);
  }
}

extern "C" void kernel_launch(void* const* d_in, const int* in_sizes, int n_in,
                              void* d_out, int out_size, void* d_ws, size_t ws_size,
                              hipStream_t stream){
  const float* x    = (const float*)d_in[0];
  const int*   ei   = (const int*)d_in[1];
  const float* W1   = (const float*)d_in[2];
  const float* as1w = (const float*)d_in[3];
  const float* ad1w = (const float*)d_in[4];
  const float* b1   = (const float*)d_in[5];
  const float* W2   = (const float*)d_in[6];
  const float* as2w = (const float*)d_in[7];
  const float* ad2w = (const float*)d_in[8];
  const float* b2   = (const float*)d_in[9];
  float* out = (float*)d_out;

  const int N = in_sizes[0] / F_IN;      // 50000
  const int E = in_sizes[1] / 2;         // 800000
  const int* srcA = ei;
  const int* dstA = ei + E;

  float* h1    = (float*)d_ws;
  float* h2    = h1    + (size_t)N*HC1;
  float* asrc1 = h2    + (size_t)N*HC1;
  float* adst1 = asrc1 + (size_t)N*HEADS;
  float* g2    = adst1 + (size_t)N*HEADS;
  float* asrc2 = g2    + (size_t)N*HID;
  float* adst2 = asrc2 + N;
  int*   deg   = (int*)(adst2 + N);
  int*   cur   = deg  + N;
  int*   offs  = cur  + N;
  int*   csr   = offs + (N + 1);

  // zero histogram + scatter cursors (deg and cur are adjacent)
  hipMemsetAsync(deg, 0, (size_t)2*N*sizeof(int), stream);

  k_deg    <<<(E+255)/256, 256, 0, stream>>>(dstA, deg, E);
  k_scan   <<<1, 1024, 0, stream>>>(deg, offs, N, E);
  k_scatter<<<(E+255)/256, 256, 0, stream>>>(srcA, dstA, offs, cur, csr, E);

  dim3 g1((N + 63)/64, HC1/64);
  k_gemm1 <<<g1, 256, 0, stream>>>(x, W1, h1, N);
  k_alpha1<<<(N*HEADS + 255)/256, 256, 0, stream>>>(h1, as1w, ad1w, asrc1, adst1, N*HEADS);
  k_agg1  <<<(N + 3)/4, 256, 0, stream>>>(h1, asrc1, adst1, offs, csr, b1, h2, N);

  k_gemm2 <<<(N + 127)/128, 256, 0, stream>>>(h2, W2, g2, N);
  k_alpha2<<<(N + 255)/256, 256, 0, stream>>>(g2, as2w, ad2w, asrc2, adst2, N);
  k_agg2  <<<(N + 3)/4, 256, 0, stream>>>(g2, asrc2, adst2, offs, csr, b2, out, N);
}

// Round 2
// 437.803 us; speedup vs baseline: 1.1340x; 1.1340x over previous
//
#include <hip/hip_runtime.h>

#define F_IN 128
#define HC1 256   // HEADS*HID
#define HID 32
#define HEADS 8

typedef short bf16x8 __attribute__((ext_vector_type(8)));
typedef float f32x4  __attribute__((ext_vector_type(4)));

__device__ __forceinline__ float lrelu(float x){ return x > 0.f ? x : 0.2f*x; }

__device__ __forceinline__ unsigned short f2b(float f){
  union { float f; unsigned u; } v; v.f = f;
  unsigned u = v.u;
  u += 0x7fffu + ((u >> 16) & 1u);   // RNE
  return (unsigned short)(u >> 16);
}
__device__ __forceinline__ float b2f(unsigned h){
  union { unsigned u; float f; } v; v.u = h << 16; return v.f;
}

// ---------------- CSR build ----------------
__global__ void k_deg(const int* __restrict__ dst, int* __restrict__ deg, int E){
  int t = blockIdx.x*blockDim.x + threadIdx.x;
  if (t < E) atomicAdd(&deg[dst[t]], 1);
}

__global__ __launch_bounds__(1024) void k_scan(const int* __restrict__ deg, int* __restrict__ offs,
                                               int N, int E){
  __shared__ int part[1024];
  int t = threadIdx.x;
  int C = (N + 1023) >> 10;
  int lo = t*C, hi = min(lo + C, N);
  int s = 0;
  for (int i = lo; i < hi; ++i) s += deg[i];
  part[t] = s;
  __syncthreads();
  for (int off = 1; off < 1024; off <<= 1){
    int v = (t >= off) ? part[t - off] : 0;
    __syncthreads();
    part[t] += v;
    __syncthreads();
  }
  int base = (t == 0) ? 0 : part[t-1];
  for (int i = lo; i < hi; ++i){ offs[i] = base; base += deg[i]; }
  if (t == 0) offs[N] = E;
}

__global__ void k_scatter(const int* __restrict__ src, const int* __restrict__ dst,
                          const int* __restrict__ offs, int* __restrict__ cur,
                          int* __restrict__ csr, int E){
  int t = blockIdx.x*blockDim.x + threadIdx.x;
  if (t < E){
    int d = dst[t];
    int p = offs[d] + atomicAdd(&cur[d], 1);
    csr[p] = src[t];
  }
}

// ---------------- conversions ----------------
__global__ void k_cvt_x(const float* __restrict__ x, unsigned short* __restrict__ xb, int NE8){
  int t = blockIdx.x*blockDim.x + threadIdx.x;
  if (t >= NE8) return;
  size_t o = (size_t)t * 8;
  float4 a = *(const float4*)(x + o);
  float4 b = *(const float4*)(x + o + 4);
  unsigned short r[8] = { f2b(a.x), f2b(a.y), f2b(a.z), f2b(a.w),
                          f2b(b.x), f2b(b.y), f2b(b.z), f2b(b.w) };
  *(uint4*)(xb + o) = *(const uint4*)r;
}

// W1[k=128][n=256] fp32 -> W1T[n=256][k=128] bf16
__global__ void k_cvt_w1t(const float* __restrict__ w1, unsigned short* __restrict__ w1t, int T){
  int t = blockIdx.x*blockDim.x + threadIdx.x;
  if (t >= T) return;
  int n = t >> 7, k = t & 127;
  w1t[t] = f2b(w1[(size_t)k*HC1 + n]);
}

// ---------------- GEMM1 (bf16 MFMA): xb[M,128] @ W1 -> h1b[M,256] bf16 ----------------
__global__ __launch_bounds__(256) void k_gemm1b(const unsigned short* __restrict__ xb,
    const unsigned short* __restrict__ w1t, unsigned short* __restrict__ h1b, int M){
  __shared__ unsigned short As[64][136];  // [m][k], +8 pad -> 2-way LDS aliasing (free)
  __shared__ unsigned short Bs[64][136];  // [n][k]
  int tid = threadIdx.x;
  int rowbase = blockIdx.x * 64;
  int colbase = blockIdx.y * 64;
  #pragma unroll
  for (int j = 0; j < 4; ++j){
    int idx = (tid + 256*j) * 8;
    int r = idx >> 7, c = idx & 127;
    int row = rowbase + r;
    uint4 va = make_uint4(0,0,0,0);
    if (row < M) va = *(const uint4*)(xb + (size_t)row*F_IN + c);
    *(uint4*)&As[r][c] = va;
    uint4 vb = *(const uint4*)(w1t + (size_t)(colbase + r)*F_IN + c);
    *(uint4*)&Bs[r][c] = vb;
  }
  __syncthreads();
  int wv = tid >> 6, lane = tid & 63;
  int m0 = (wv >> 1) * 32, n0 = (wv & 1) * 32;
  int lr = lane & 15, lq = lane >> 4;
  f32x4 acc[2][2] = {};
  #pragma unroll
  for (int k0 = 0; k0 < F_IN; k0 += 32){
    bf16x8 a0 = *(const bf16x8*)&As[m0 + lr][k0 + lq*8];
    bf16x8 a1 = *(const bf16x8*)&As[m0 + 16 + lr][k0 + lq*8];
    bf16x8 b0 = *(const bf16x8*)&Bs[n0 + lr][k0 + lq*8];
    bf16x8 b1 = *(const bf16x8*)&Bs[n0 + 16 + lr][k0 + lq*8];
    acc[0][0] = __builtin_amdgcn_mfma_f32_16x16x32_bf16(a0, b0, acc[0][0], 0, 0, 0);
    acc[0][1] = __builtin_amdgcn_mfma_f32_16x16x32_bf16(a0, b1, acc[0][1], 0, 0, 0);
    acc[1][0] = __builtin_amdgcn_mfma_f32_16x16x32_bf16(a1, b0, acc[1][0], 0, 0, 0);
    acc[1][1] = __builtin_amdgcn_mfma_f32_16x16x32_bf16(a1, b1, acc[1][1], 0, 0, 0);
  }
  #pragma unroll
  for (int i = 0; i < 2; ++i){
    #pragma unroll
    for (int j = 0; j < 2; ++j){
      #pragma unroll
      for (int r = 0; r < 4; ++r){
        int row = rowbase + m0 + i*16 + lq*4 + r;
        int col = colbase + n0 + j*16 + lr;
        if (row < M) h1b[(size_t)row*HC1 + col] = f2b(acc[i][j][r]);
      }
    }
  }
}

// ---------------- GEMM2: h2[M,256] @ W2[256,32] -> g2[M,32] (fp32) ----------------
__global__ __launch_bounds__(256) void k_gemm2(const float* __restrict__ A, const float* __restrict__ B,
                                               float* __restrict__ C, int M){
  __shared__ float As[64][132];
  __shared__ float Bs[64][36];
  int tid = threadIdx.x;
  int m0 = (tid >> 3) << 2;
  int n0 = (tid & 7) << 2;
  int rowbase = blockIdx.x * 128;
  float acc[4][4] = {};
  for (int k0 = 0; k0 < HC1; k0 += 64){
    #pragma unroll
    for (int j = 0; j < 8; ++j){
      int q = tid + 256*j;
      int r = q >> 4;
      int kk = (q & 15) << 2;
      int row = rowbase + r;
      float4 va = make_float4(0.f,0.f,0.f,0.f);
      if (row < M) va = *(const float4*)(A + (size_t)row*HC1 + k0 + kk);
      As[kk+0][r] = va.x; As[kk+1][r] = va.y; As[kk+2][r] = va.z; As[kk+3][r] = va.w;
    }
    #pragma unroll
    for (int j = 0; j < 2; ++j){
      int q = tid + 256*j;
      int r = q >> 3;
      int nn = (q & 7) << 2;
      *(float4*)&Bs[r][nn] = *(const float4*)(B + (size_t)(k0 + r)*HID + nn);
    }
    __syncthreads();
    #pragma unroll
    for (int k = 0; k < 64; ++k){
      float4 a = *(const float4*)&As[k][m0];
      float4 b = *(const float4*)&Bs[k][n0];
      acc[0][0] += a.x*b.x; acc[0][1] += a.x*b.y; acc[0][2] += a.x*b.z; acc[0][3] += a.x*b.w;
      acc[1][0] += a.y*b.x; acc[1][1] += a.y*b.y; acc[1][2] += a.y*b.z; acc[1][3] += a.y*b.w;
      acc[2][0] += a.z*b.x; acc[2][1] += a.z*b.y; acc[2][2] += a.z*b.z; acc[2][3] += a.z*b.w;
      acc[3][0] += a.w*b.x; acc[3][1] += a.w*b.y; acc[3][2] += a.w*b.z; acc[3][3] += a.w*b.w;
    }
    __syncthreads();
  }
  #pragma unroll
  for (int i = 0; i < 4; ++i){
    int row = rowbase + m0 + i;
    if (row < M)
      *(float4*)(C + (size_t)row*HID + n0) =
        make_float4(acc[i][0], acc[i][1], acc[i][2], acc[i][3]);
  }
}

// ---------------- per-node alpha dots ----------------
__global__ void k_alpha1(const unsigned short* __restrict__ h1b, const float* __restrict__ a_src,
                         const float* __restrict__ a_dst, float* __restrict__ os,
                         float* __restrict__ od, int NH){
  int t = blockIdx.x*blockDim.x + threadIdx.x;
  if (t >= NH) return;
  int h = t & 7;
  const float4* sp = (const float4*)(a_src + h*HID);
  const float4* dp = (const float4*)(a_dst + h*HID);
  float ss = 0.f, dd = 0.f;
  #pragma unroll
  for (int j = 0; j < 4; ++j){
    uint4 u = *(const uint4*)(h1b + (size_t)t*HID + j*8);
    float v0 = b2f(u.x & 0xffffu), v1 = b2f(u.x >> 16);
    float v2 = b2f(u.y & 0xffffu), v3 = b2f(u.y >> 16);
    float v4 = b2f(u.z & 0xffffu), v5 = b2f(u.z >> 16);
    float v6 = b2f(u.w & 0xffffu), v7 = b2f(u.w >> 16);
    float4 s0 = sp[2*j], s1 = sp[2*j+1];
    float4 d0 = dp[2*j], d1 = dp[2*j+1];
    ss += v0*s0.x + v1*s0.y + v2*s0.z + v3*s0.w + v4*s1.x + v5*s1.y + v6*s1.z + v7*s1.w;
    dd += v0*d0.x + v1*d0.y + v2*d0.z + v3*d0.w + v4*d1.x + v5*d1.y + v6*d1.z + v7*d1.w;
  }
  os[t] = ss; od[t] = dd;
}

__global__ void k_alpha2(const float* __restrict__ g2, const float* __restrict__ a_src,
                         const float* __restrict__ a_dst, float* __restrict__ os,
                         float* __restrict__ od, int N){
  int t = blockIdx.x*blockDim.x + threadIdx.x;
  if (t >= N) return;
  const float4* hp = (const float4*)(g2 + (size_t)t*HID);
  const float4* sp = (const float4*)a_src;
  const float4* dp = (const float4*)a_dst;
  float ss = 0.f, dd = 0.f;
  #pragma unroll
  for (int j = 0; j < 8; ++j){
    float4 v = hp[j], s = sp[j], d = dp[j];
    ss += v.x*s.x + v.y*s.y + v.z*s.z + v.w*s.w;
    dd += v.x*d.x + v.y*d.y + v.z*d.z + v.w*d.w;
  }
  os[t] = ss; od[t] = dd;
}

// ---------------- layer-1 aggregation: wave per node, bf16 gather ----------------
__global__ __launch_bounds__(256) void k_agg1(const unsigned short* __restrict__ h1b,
    const float* __restrict__ as1, const float* __restrict__ ad1,
    const int* __restrict__ offs, const int* __restrict__ csr,
    const float* __restrict__ b1, float* __restrict__ h2, int N){
  int w = (blockIdx.x*blockDim.x + threadIdx.x) >> 6;
  if (w >= N) return;
  int lane = threadIdx.x & 63;
  int c0 = lane << 2;        // element col 0..252
  int h = lane >> 3;         // head 0..7
  int n = w;
  float adv = ad1[n*HEADS + h];
  // implicit self-loop (src = n)
  float m = lrelu(as1[n*HEADS + h] + adv);
  float l = 1.f;
  uint2 sv = *(const uint2*)(h1b + (size_t)n*HC1 + c0);
  float4 acc = make_float4(b2f(sv.x & 0xffffu), b2f(sv.x >> 16),
                           b2f(sv.y & 0xffffu), b2f(sv.y >> 16));
  int s0 = offs[n], s1 = offs[n+1];
  for (int i = s0; i < s1; ++i){
    int s = csr[i];
    float e = lrelu(as1[s*HEADS + h] + adv);
    uint2 u = *(const uint2*)(h1b + (size_t)s*HC1 + c0);
    float vx = b2f(u.x & 0xffffu), vy = b2f(u.x >> 16);
    float vz = b2f(u.y & 0xffffu), vw = b2f(u.y >> 16);
    float mn = fmaxf(m, e);
    float sc = __expf(m - mn);
    float p  = __expf(e - mn);
    l = l*sc + p;
    acc.x = acc.x*sc + p*vx;
    acc.y = acc.y*sc + p*vy;
    acc.z = acc.z*sc + p*vz;
    acc.w = acc.w*sc + p*vw;
    m = mn;
  }
  float rl = 1.f / l;
  float4 bb = *(const float4*)(b1 + c0);
  float4 o;
  o.x = acc.x*rl + bb.x; o.y = acc.y*rl + bb.y;
  o.z = acc.z*rl + bb.z; o.w = acc.w*rl + bb.w;
  o.x = o.x > 0.f ? o.x : __expf(o.x) - 1.f;
  o.y = o.y > 0.f ? o.y : __expf(o.y) - 1.f;
  o.z = o.z > 0.f ? o.z : __expf(o.z) - 1.f;
  o.w = o.w > 0.f ? o.w : __expf(o.w) - 1.f;
  *(float4*)(h2 + (size_t)n*HC1 + c0) = o;
}

// ---------------- layer-2 aggregation ----------------
__global__ __launch_bounds__(256) void k_agg2(const float* __restrict__ g2,
    const float* __restrict__ as2, const float* __restrict__ ad2,
    const int* __restrict__ offs, const int* __restrict__ csr,
    const float* __restrict__ b2, float* __restrict__ out, int N){
  int w = (blockIdx.x*blockDim.x + threadIdx.x) >> 6;
  if (w >= N) return;
  int lane = threadIdx.x & 63;
  int g = lane >> 3;
  int c0 = (lane & 7) << 2;
  int n = w;
  float adv = ad2[n];
  float m = -1e30f, l = 0.f;
  float4 acc = make_float4(0.f,0.f,0.f,0.f);
  if (g == 0){
    m = lrelu(as2[n] + adv);
    l = 1.f;
    acc = *(const float4*)(g2 + (size_t)n*HID + c0);
  }
  int s0 = offs[n], s1 = offs[n+1];
  for (int i = s0 + g; i < s1; i += 8){
    int s = csr[i];
    float e = lrelu(as2[s] + adv);
    float4 v = *(const float4*)(g2 + (size_t)s*HID + c0);
    float mn = fmaxf(m, e);
    float sc = __expf(m - mn);
    float p  = __expf(e - mn);
    l = l*sc + p;
    acc.x = acc.x*sc + p*v.x;
    acc.y = acc.y*sc + p*v.y;
    acc.z = acc.z*sc + p*v.z;
    acc.w = acc.w*sc + p*v.w;
    m = mn;
  }
  #pragma unroll
  for (int mask = 8; mask <= 32; mask <<= 1){
    float mo = __shfl_xor(m, mask, 64);
    float lo = __shfl_xor(l, mask, 64);
    float ax = __shfl_xor(acc.x, mask, 64);
    float ay = __shfl_xor(acc.y, mask, 64);
    float az = __shfl_xor(acc.z, mask, 64);
    float aw = __shfl_xor(acc.w, mask, 64);
    float mn = fmaxf(m, mo);
    float sc = __expf(m - mn), so = __expf(mo - mn);
    l = l*sc + lo*so;
    acc.x = acc.x*sc + ax*so;
    acc.y = acc.y*sc + ay*so;
    acc.z = acc.z*sc + az*so;
    acc.w = acc.w*sc + aw*so;
    m = mn;
  }
  if (g == 0){
    float rl = 1.f/l;
    float4 bb = *(const float4*)(b2 + c0);
    *(float4*)(out + (size_t)n*HID + c0) =
      make_float4(acc.x*rl + bb.x, acc.y*rl + bb.y, acc.z*rl + bb.z, acc.w*rl + bb.w);
  }
}

extern "C" void kernel_launch(void* const* d_in, const int* in_sizes, int n_in,
                              void* d_out, int out_size, void* d_ws, size_t ws_size,
                              hipStream_t stream){
  const float* x    = (const float*)d_in[0];
  const int*   ei   = (const int*)d_in[1];
  const float* W1   = (const float*)d_in[2];
  const float* as1w = (const float*)d_in[3];
  const float* ad1w = (const float*)d_in[4];
  const float* b1   = (const float*)d_in[5];
  const float* W2   = (const float*)d_in[6];
  const float* as2w = (const float*)d_in[7];
  const float* ad2w = (const float*)d_in[8];
  const float* b2   = (const float*)d_in[9];
  float* out = (float*)d_out;

  const int N = in_sizes[0] / F_IN;      // 50000
  const int E = in_sizes[1] / 2;         // 800000
  const int* srcA = ei;
  const int* dstA = ei + E;

  float* h2    = (float*)d_ws;                     // N*256 f32
  float* g2    = h2    + (size_t)N*HC1;            // N*32 f32
  float* asrc1 = g2    + (size_t)N*HID;            // N*8
  float* adst1 = asrc1 + (size_t)N*HEADS;          // N*8
  float* asrc2 = adst1 + (size_t)N*HEADS;          // N
  float* adst2 = asrc2 + N;                        // N
  unsigned short* xb   = (unsigned short*)(adst2 + N);   // N*128 bf16
  unsigned short* w1tb = xb + (size_t)N*F_IN;            // 256*128 bf16
  unsigned short* h1b  = w1tb + (size_t)HC1*F_IN;        // N*256 bf16
  int* deg  = (int*)(h1b + (size_t)N*HC1);
  int* cur  = deg  + N;
  int* offs = cur  + N;
  int* csr  = offs + (N + 1);

  hipMemsetAsync(deg, 0, (size_t)2*N*sizeof(int), stream);

  k_deg    <<<(E+255)/256, 256, 0, stream>>>(dstA, deg, E);
  k_scan   <<<1, 1024, 0, stream>>>(deg, offs, N, E);
  k_scatter<<<(E+255)/256, 256, 0, stream>>>(srcA, dstA, offs, cur, csr, E);

  int ne8 = N*F_IN/8;
  k_cvt_x  <<<(ne8+255)/256, 256, 0, stream>>>(x, xb, ne8);
  k_cvt_w1t<<<(HC1*F_IN+255)/256, 256, 0, stream>>>(W1, w1tb, HC1*F_IN);

  dim3 g1((N + 63)/64, HC1/64);
  k_gemm1b<<<g1, 256, 0, stream>>>(xb, w1tb, h1b, N);
  k_alpha1<<<(N*HEADS + 255)/256, 256, 0, stream>>>(h1b, as1w, ad1w, asrc1, adst1, N*HEADS);
  k_agg1  <<<(N + 3)/4, 256, 0, stream>>>(h1b, asrc1, adst1, offs, csr, b1, h2, N);

  k_gemm2 <<<(N + 127)/128, 256, 0, stream>>>(h2, W2, g2, N);
  k_alpha2<<<(N + 255)/256, 256, 0, stream>>>(g2, as2w, ad2w, asrc2, adst2, N);
  k_agg2  <<<(N + 3)/4, 256, 0, stream>>>(g2, asrc2, adst2, offs, csr, b2, out, N);
}

// Round 3
// 387.521 us; speedup vs baseline: 1.2811x; 1.1298x over previous
//
#include <hip/hip_runtime.h>

#define F_IN 128
#define HC1 256   // HEADS*HID
#define HID 32
#define HEADS 8

typedef short bf16x8 __attribute__((ext_vector_type(8)));
typedef float f32x4  __attribute__((ext_vector_type(4)));

__device__ __forceinline__ float lrelu(float x){ return x > 0.f ? x : 0.2f*x; }

__device__ __forceinline__ unsigned short f2b(float f){
  union { float f; unsigned u; } v; v.f = f;
  unsigned u = v.u;
  u += 0x7fffu + ((u >> 16) & 1u);   // RNE
  return (unsigned short)(u >> 16);
}
__device__ __forceinline__ float blo(unsigned u){
  union { unsigned u; float f; } v; v.u = u << 16; return v.f;
}
__device__ __forceinline__ float bhi(unsigned u){
  union { unsigned u; float f; } v; v.u = u & 0xffff0000u; return v.f;
}

// ---------------- CSR build ----------------
__global__ void k_deg(const int* __restrict__ dst, int* __restrict__ deg, int E){
  int t = blockIdx.x*blockDim.x + threadIdx.x;
  if (t < E) atomicAdd(&deg[dst[t]], 1);
}

__global__ __launch_bounds__(1024) void k_scan(const int* __restrict__ deg, int* __restrict__ offs,
                                               int N, int E){
  __shared__ int part[1024];
  int t = threadIdx.x;
  int C = (N + 1023) >> 10;
  int lo = t*C, hi = min(lo + C, N);
  int s = 0;
  for (int i = lo; i < hi; ++i) s += deg[i];
  part[t] = s;
  __syncthreads();
  for (int off = 1; off < 1024; off <<= 1){
    int v = (t >= off) ? part[t - off] : 0;
    __syncthreads();
    part[t] += v;
    __syncthreads();
  }
  int base = (t == 0) ? 0 : part[t-1];
  for (int i = lo; i < hi; ++i){ offs[i] = base; base += deg[i]; }
  if (t == 0) offs[N] = E;
}

__global__ void k_scatter(const int* __restrict__ src, const int* __restrict__ dst,
                          const int* __restrict__ offs, int* __restrict__ cur,
                          int* __restrict__ csr, int E){
  int t = blockIdx.x*blockDim.x + threadIdx.x;
  if (t < E){
    int d = dst[t];
    int p = offs[d] + atomicAdd(&cur[d], 1);
    csr[p] = src[t];
  }
}

// ---------------- conversions ----------------
__global__ void k_cvt_x(const float* __restrict__ x, unsigned short* __restrict__ xb, int NE8){
  int t = blockIdx.x*blockDim.x + threadIdx.x;
  if (t >= NE8) return;
  size_t o = (size_t)t * 8;
  float4 a = *(const float4*)(x + o);
  float4 b = *(const float4*)(x + o + 4);
  unsigned short r[8] = { f2b(a.x), f2b(a.y), f2b(a.z), f2b(a.w),
                          f2b(b.x), f2b(b.y), f2b(b.z), f2b(b.w) };
  *(uint4*)(xb + o) = *(const uint4*)r;
}

// W1[k=128][n=256] -> W1T[n=256][k=128] bf16
__global__ void k_cvt_w1t(const float* __restrict__ w1, unsigned short* __restrict__ w1t, int T){
  int t = blockIdx.x*blockDim.x + threadIdx.x;
  if (t >= T) return;
  int n = t >> 7, k = t & 127;
  w1t[t] = f2b(w1[(size_t)k*HC1 + n]);
}

// W2[k=256][n=32] -> W2T[n=32][k=256] bf16
__global__ void k_cvt_w2t(const float* __restrict__ w2, unsigned short* __restrict__ w2t, int T){
  int t = blockIdx.x*blockDim.x + threadIdx.x;
  if (t >= T) return;
  int n = t >> 8, k = t & 255;
  w2t[t] = f2b(w2[(size_t)k*HID + n]);
}

// ---------------- GEMM1 (bf16 MFMA): xb[M,128] @ W1 -> h1b[M,256] bf16 ----------------
__global__ __launch_bounds__(256) void k_gemm1b(const unsigned short* __restrict__ xb,
    const unsigned short* __restrict__ w1t, unsigned short* __restrict__ h1b, int M){
  __shared__ unsigned short As[64][136];  // [m][k], +8 pad (2-way aliasing is free)
  __shared__ unsigned short Bs[64][136];  // [n][k]
  int tid = threadIdx.x;
  int rowbase = blockIdx.x * 64;
  int colbase = blockIdx.y * 64;
  #pragma unroll
  for (int j = 0; j < 4; ++j){
    int idx = (tid + 256*j) * 8;
    int r = idx >> 7, c = idx & 127;
    int row = rowbase + r;
    uint4 va = make_uint4(0,0,0,0);
    if (row < M) va = *(const uint4*)(xb + (size_t)row*F_IN + c);
    *(uint4*)&As[r][c] = va;
    uint4 vb = *(const uint4*)(w1t + (size_t)(colbase + r)*F_IN + c);
    *(uint4*)&Bs[r][c] = vb;
  }
  __syncthreads();
  int wv = tid >> 6, lane = tid & 63;
  int m0 = (wv >> 1) * 32, n0 = (wv & 1) * 32;
  int lr = lane & 15, lq = lane >> 4;
  f32x4 acc[2][2] = {};
  #pragma unroll
  for (int k0 = 0; k0 < F_IN; k0 += 32){
    bf16x8 a0 = *(const bf16x8*)&As[m0 + lr][k0 + lq*8];
    bf16x8 a1 = *(const bf16x8*)&As[m0 + 16 + lr][k0 + lq*8];
    bf16x8 b0 = *(const bf16x8*)&Bs[n0 + lr][k0 + lq*8];
    bf16x8 b1 = *(const bf16x8*)&Bs[n0 + 16 + lr][k0 + lq*8];
    acc[0][0] = __builtin_amdgcn_mfma_f32_16x16x32_bf16(a0, b0, acc[0][0], 0, 0, 0);
    acc[0][1] = __builtin_amdgcn_mfma_f32_16x16x32_bf16(a0, b1, acc[0][1], 0, 0, 0);
    acc[1][0] = __builtin_amdgcn_mfma_f32_16x16x32_bf16(a1, b0, acc[1][0], 0, 0, 0);
    acc[1][1] = __builtin_amdgcn_mfma_f32_16x16x32_bf16(a1, b1, acc[1][1], 0, 0, 0);
  }
  #pragma unroll
  for (int i = 0; i < 2; ++i){
    #pragma unroll
    for (int j = 0; j < 2; ++j){
      #pragma unroll
      for (int r = 0; r < 4; ++r){
        int row = rowbase + m0 + i*16 + lq*4 + r;
        int col = colbase + n0 + j*16 + lr;
        if (row < M) h1b[(size_t)row*HC1 + col] = f2b(acc[i][j][r]);
      }
    }
  }
}

// ---------------- GEMM2 (bf16 MFMA, no LDS): h2b[M,256] @ W2T -> g2 f32 + g2b bf16 ----
__global__ __launch_bounds__(256) void k_gemm2b(const unsigned short* __restrict__ h2b,
    const unsigned short* __restrict__ w2t, float* __restrict__ g2,
    unsigned short* __restrict__ g2b, int M){
  int tid = threadIdx.x;
  int wv = tid >> 6, lane = tid & 63;
  int lr = lane & 15, lq = lane >> 4;
  int m0 = blockIdx.x*64 + wv*16;
  int arow = m0 + lr;
  bool ok = arow < M;
  const unsigned short* ap  = h2b + (size_t)arow*HC1 + lq*8;
  const unsigned short* b0p = w2t + (size_t)lr*HC1 + lq*8;
  const unsigned short* b1p = w2t + (size_t)(16 + lr)*HC1 + lq*8;
  f32x4 acc0 = {}, acc1 = {};
  #pragma unroll
  for (int k0 = 0; k0 < HC1; k0 += 32){
    bf16x8 a  = ok ? *(const bf16x8*)(ap + k0) : (bf16x8){0,0,0,0,0,0,0,0};
    bf16x8 b0 = *(const bf16x8*)(b0p + k0);
    bf16x8 b1 = *(const bf16x8*)(b1p + k0);
    acc0 = __builtin_amdgcn_mfma_f32_16x16x32_bf16(a, b0, acc0, 0, 0, 0);
    acc1 = __builtin_amdgcn_mfma_f32_16x16x32_bf16(a, b1, acc1, 0, 0, 0);
  }
  #pragma unroll
  for (int r = 0; r < 4; ++r){
    int orow = m0 + lq*4 + r;
    if (orow < M){
      g2 [(size_t)orow*HID + lr]       = acc0[r];
      g2 [(size_t)orow*HID + 16 + lr]  = acc1[r];
      g2b[(size_t)orow*HID + lr]       = f2b(acc0[r]);
      g2b[(size_t)orow*HID + 16 + lr]  = f2b(acc1[r]);
    }
  }
}

// ---------------- per-node alpha dots ----------------
__global__ void k_alpha1(const unsigned short* __restrict__ h1b, const float* __restrict__ a_src,
                         const float* __restrict__ a_dst, float* __restrict__ os,
                         float* __restrict__ od, int NH){
  int t = blockIdx.x*blockDim.x + threadIdx.x;
  if (t >= NH) return;
  int h = t & 7;
  const float4* sp = (const float4*)(a_src + h*HID);
  const float4* dp = (const float4*)(a_dst + h*HID);
  float ss = 0.f, dd = 0.f;
  #pragma unroll
  for (int j = 0; j < 4; ++j){
    uint4 u = *(const uint4*)(h1b + (size_t)t*HID + j*8);
    float v0 = blo(u.x), v1 = bhi(u.x);
    float v2 = blo(u.y), v3 = bhi(u.y);
    float v4 = blo(u.z), v5 = bhi(u.z);
    float v6 = blo(u.w), v7 = bhi(u.w);
    float4 s0 = sp[2*j], s1 = sp[2*j+1];
    float4 d0 = dp[2*j], d1 = dp[2*j+1];
    ss += v0*s0.x + v1*s0.y + v2*s0.z + v3*s0.w + v4*s1.x + v5*s1.y + v6*s1.z + v7*s1.w;
    dd += v0*d0.x + v1*d0.y + v2*d0.z + v3*d0.w + v4*d1.x + v5*d1.y + v6*d1.z + v7*d1.w;
  }
  os[t] = ss; od[t] = dd;
}

__global__ void k_alpha2(const float* __restrict__ g2, const float* __restrict__ a_src,
                         const float* __restrict__ a_dst, float* __restrict__ os,
                         float* __restrict__ od, int N){
  int t = blockIdx.x*blockDim.x + threadIdx.x;
  if (t >= N) return;
  const float4* hp = (const float4*)(g2 + (size_t)t*HID);
  const float4* sp = (const float4*)a_src;
  const float4* dp = (const float4*)a_dst;
  float ss = 0.f, dd = 0.f;
  #pragma unroll
  for (int j = 0; j < 8; ++j){
    float4 v = hp[j], s = sp[j], d = dp[j];
    ss += v.x*s.x + v.y*s.y + v.z*s.z + v.w*s.w;
    dd += v.x*d.x + v.y*d.y + v.z*d.z + v.w*d.w;
  }
  os[t] = ss; od[t] = dd;
}

// ---------------- layer-1 aggregation: wave/node, plain-exp softmax, bf16 ----------------
__global__ __launch_bounds__(256) void k_agg1(const unsigned short* __restrict__ h1b,
    const float* __restrict__ as1, const float* __restrict__ ad1,
    const int* __restrict__ offs, const int* __restrict__ csr,
    const float* __restrict__ b1, unsigned short* __restrict__ h2b, int N){
  int w = (blockIdx.x*blockDim.x + threadIdx.x) >> 6;
  if (w >= N) return;
  int lane = threadIdx.x & 63;
  int c0 = lane << 2;        // element col 0..252
  int h = lane >> 3;         // head 0..7
  float adv = ad1[w*HEADS + h];
  // implicit self-loop
  float p0 = __expf(lrelu(as1[w*HEADS + h] + adv));
  float l = p0;
  uint2 sv = *(const uint2*)(h1b + (size_t)w*HC1 + c0);
  float4 acc = make_float4(p0*blo(sv.x), p0*bhi(sv.x), p0*blo(sv.y), p0*bhi(sv.y));
  int i = offs[w], e1 = offs[w+1];
  for (; i + 2 <= e1; i += 2){
    int sA = csr[i], sB = csr[i+1];
    float aA = as1[sA*HEADS + h];
    float aB = as1[sB*HEADS + h];
    uint2 uA = *(const uint2*)(h1b + (size_t)sA*HC1 + c0);
    uint2 uB = *(const uint2*)(h1b + (size_t)sB*HC1 + c0);
    float pA = __expf(lrelu(aA + adv));
    float pB = __expf(lrelu(aB + adv));
    l += pA + pB;
    acc.x += pA*blo(uA.x) + pB*blo(uB.x);
    acc.y += pA*bhi(uA.x) + pB*bhi(uB.x);
    acc.z += pA*blo(uA.y) + pB*blo(uB.y);
    acc.w += pA*bhi(uA.y) + pB*bhi(uB.y);
  }
  if (i < e1){
    int s = csr[i];
    float p = __expf(lrelu(as1[s*HEADS + h] + adv));
    uint2 u = *(const uint2*)(h1b + (size_t)s*HC1 + c0);
    l += p;
    acc.x += p*blo(u.x); acc.y += p*bhi(u.x);
    acc.z += p*blo(u.y); acc.w += p*bhi(u.y);
  }
  float rl = 1.f / l;
  float4 bb = *(const float4*)(b1 + c0);
  float4 o;
  o.x = acc.x*rl + bb.x; o.y = acc.y*rl + bb.y;
  o.z = acc.z*rl + bb.z; o.w = acc.w*rl + bb.w;
  o.x = o.x > 0.f ? o.x : __expf(o.x) - 1.f;
  o.y = o.y > 0.f ? o.y : __expf(o.y) - 1.f;
  o.z = o.z > 0.f ? o.z : __expf(o.z) - 1.f;
  o.w = o.w > 0.f ? o.w : __expf(o.w) - 1.f;
  unsigned lo = (unsigned)f2b(o.x) | ((unsigned)f2b(o.y) << 16);
  unsigned hi = (unsigned)f2b(o.z) | ((unsigned)f2b(o.w) << 16);
  *(uint2*)(h2b + (size_t)w*HC1 + c0) = make_uint2(lo, hi);
}

// ---------------- layer-2 aggregation: wave/node, 8 edge-groups, bf16 gather ----------
__global__ __launch_bounds__(256) void k_agg2(const unsigned short* __restrict__ g2b,
    const float* __restrict__ as2, const float* __restrict__ ad2,
    const int* __restrict__ offs, const int* __restrict__ csr,
    const float* __restrict__ b2, float* __restrict__ out, int N){
  int w = (blockIdx.x*blockDim.x + threadIdx.x) >> 6;
  if (w >= N) return;
  int lane = threadIdx.x & 63;
  int g = lane >> 3;          // edge group 0..7
  int c0 = (lane & 7) << 2;   // col 0..28
  float adv = ad2[w];
  float l = 0.f;
  float4 acc = make_float4(0.f,0.f,0.f,0.f);
  if (g == 0){
    float p0 = __expf(lrelu(as2[w] + adv));
    l = p0;
    uint2 sv = *(const uint2*)(g2b + (size_t)w*HID + c0);
    acc = make_float4(p0*blo(sv.x), p0*bhi(sv.x), p0*blo(sv.y), p0*bhi(sv.y));
  }
  int s0 = offs[w], e1 = offs[w+1];
  for (int i = s0 + g; i < e1; i += 8){
    int s = csr[i];
    float p = __expf(lrelu(as2[s] + adv));
    uint2 u = *(const uint2*)(g2b + (size_t)s*HID + c0);
    l += p;
    acc.x += p*blo(u.x); acc.y += p*bhi(u.x);
    acc.z += p*blo(u.y); acc.w += p*bhi(u.y);
  }
  #pragma unroll
  for (int mask = 8; mask <= 32; mask <<= 1){
    l     += __shfl_xor(l, mask, 64);
    acc.x += __shfl_xor(acc.x, mask, 64);
    acc.y += __shfl_xor(acc.y, mask, 64);
    acc.z += __shfl_xor(acc.z, mask, 64);
    acc.w += __shfl_xor(acc.w, mask, 64);
  }
  if (g == 0){
    float rl = 1.f/l;
    float4 bb = *(const float4*)(b2 + c0);
    *(float4*)(out + (size_t)w*HID + c0) =
      make_float4(acc.x*rl + bb.x, acc.y*rl + bb.y, acc.z*rl + bb.z, acc.w*rl + bb.w);
  }
}

extern "C" void kernel_launch(void* const* d_in, const int* in_sizes, int n_in,
                              void* d_out, int out_size, void* d_ws, size_t ws_size,
                              hipStream_t stream){
  const float* x    = (const float*)d_in[0];
  const int*   ei   = (const int*)d_in[1];
  const float* W1   = (const float*)d_in[2];
  const float* as1w = (const float*)d_in[3];
  const float* ad1w = (const float*)d_in[4];
  const float* b1   = (const float*)d_in[5];
  const float* W2   = (const float*)d_in[6];
  const float* as2w = (const float*)d_in[7];
  const float* ad2w = (const float*)d_in[8];
  const float* b2   = (const float*)d_in[9];
  float* out = (float*)d_out;

  const int N = in_sizes[0] / F_IN;      // 50000
  const int E = in_sizes[1] / 2;         // 800000
  const int* srcA = ei;
  const int* dstA = ei + E;

  float* g2    = (float*)d_ws;                     // N*32 f32
  float* asrc1 = g2    + (size_t)N*HID;            // N*8
  float* adst1 = asrc1 + (size_t)N*HEADS;          // N*8
  float* asrc2 = adst1 + (size_t)N*HEADS;          // N
  float* adst2 = asrc2 + N;                        // N
  unsigned short* xb   = (unsigned short*)(adst2 + N);   // N*128 bf16
  unsigned short* w1tb = xb   + (size_t)N*F_IN;          // 256*128
  unsigned short* w2tb = w1tb + (size_t)HC1*F_IN;        // 32*256
  unsigned short* h1b  = w2tb + (size_t)HID*HC1;         // N*256
  unsigned short* h2b  = h1b  + (size_t)N*HC1;           // N*256
  unsigned short* g2b  = h2b  + (size_t)N*HC1;           // N*32
  int* deg  = (int*)(g2b + (size_t)N*HID);
  int* cur  = deg  + N;
  int* offs = cur  + N;
  int* csr  = offs + (N + 1);

  hipMemsetAsync(deg, 0, (size_t)2*N*sizeof(int), stream);

  k_deg    <<<(E+255)/256, 256, 0, stream>>>(dstA, deg, E);
  k_scan   <<<1, 1024, 0, stream>>>(deg, offs, N, E);
  k_scatter<<<(E+255)/256, 256, 0, stream>>>(srcA, dstA, offs, cur, csr, E);

  int ne8 = N*F_IN/8;
  k_cvt_x  <<<(ne8+255)/256, 256, 0, stream>>>(x, xb, ne8);
  k_cvt_w1t<<<(HC1*F_IN+255)/256, 256, 0, stream>>>(W1, w1tb, HC1*F_IN);
  k_cvt_w2t<<<(HID*HC1+255)/256, 256, 0, stream>>>(W2, w2tb, HID*HC1);

  dim3 g1((N + 63)/64, HC1/64);
  k_gemm1b<<<g1, 256, 0, stream>>>(xb, w1tb, h1b, N);
  k_alpha1<<<(N*HEADS + 255)/256, 256, 0, stream>>>(h1b, as1w, ad1w, asrc1, adst1, N*HEADS);
  k_agg1  <<<(N + 3)/4, 256, 0, stream>>>(h1b, asrc1, adst1, offs, csr, b1, h2b, N);

  k_gemm2b<<<(N + 63)/64, 256, 0, stream>>>(h2b, w2tb, g2, g2b, N);
  k_alpha2<<<(N + 255)/256, 256, 0, stream>>>(g2, as2w, ad2w, asrc2, adst2, N);
  k_agg2  <<<(N + 3)/4, 256, 0, stream>>>(g2b, asrc2, adst2, offs, csr, b2, out, N);
}

// Round 4
// 315.884 us; speedup vs baseline: 1.5717x; 1.2268x over previous
//
#include <hip/hip_runtime.h>

#define F_IN 128
#define HC1 256   // HEADS*HID
#define HID 32
#define HEADS 8

typedef short bf16x8 __attribute__((ext_vector_type(8)));
typedef float f32x4  __attribute__((ext_vector_type(4)));

__device__ __forceinline__ float lrelu(float x){ return x > 0.f ? x : 0.2f*x; }

__device__ __forceinline__ unsigned short f2b(float f){
  union { float f; unsigned u; } v; v.f = f;
  unsigned u = v.u;
  u += 0x7fffu + ((u >> 16) & 1u);   // RNE
  return (unsigned short)(u >> 16);
}
__device__ __forceinline__ float blo(unsigned u){
  union { unsigned u; float f; } v; v.u = u << 16; return v.f;
}
__device__ __forceinline__ float bhi(unsigned u){
  union { unsigned u; float f; } v; v.u = u & 0xffff0000u; return v.f;
}

// ---------------- CSR build ----------------
__global__ void k_deg(const int* __restrict__ dst, int* __restrict__ deg, int E){
  int t = blockIdx.x*blockDim.x + threadIdx.x;
  if (t < E) atomicAdd(&deg[dst[t]], 1);
}

// block-level exclusive-offset allocation: LDS scan + one atomic per block.
// Region order across blocks is nondeterministic; agg reads [offs[n], offs[n]+deg[n]).
__global__ __launch_bounds__(256) void k_alloc(const int* __restrict__ deg,
    int* __restrict__ offs, int* __restrict__ gcur, int N){
  __shared__ int sh[256];
  __shared__ int sbase;
  int t = threadIdx.x;
  int n = blockIdx.x*256 + t;
  int d = (n < N) ? deg[n] : 0;
  sh[t] = d;
  __syncthreads();
  #pragma unroll
  for (int off = 1; off < 256; off <<= 1){
    int v = (t >= off) ? sh[t - off] : 0;
    __syncthreads();
    sh[t] += v;
    __syncthreads();
  }
  if (t == 255) sbase = atomicAdd(gcur, sh[255]);
  __syncthreads();
  if (n < N) offs[n] = sbase + sh[t] - d;   // exclusive prefix
}

__global__ void k_scatter(const int* __restrict__ src, const int* __restrict__ dst,
                          const int* __restrict__ offs, int* __restrict__ cur,
                          int* __restrict__ csr, int E){
  int t = blockIdx.x*blockDim.x + threadIdx.x;
  if (t < E){
    int d = dst[t];
    int p = offs[d] + atomicAdd(&cur[d], 1);
    csr[p] = src[t];
  }
}

// ---------------- weight conversions (W1T + W2T in one kernel) ----------------
__global__ void k_cvt_w(const float* __restrict__ w1, const float* __restrict__ w2,
                        unsigned short* __restrict__ w1t, unsigned short* __restrict__ w2t){
  int t = blockIdx.x*blockDim.x + threadIdx.x;
  if (t < HC1*F_IN){                 // W1[k=128][n=256] -> W1T[n][k]
    int n = t >> 7, k = t & 127;
    w1t[t] = f2b(w1[(size_t)k*HC1 + n]);
  } else {
    int u = t - HC1*F_IN;            // W2[k=256][n=32] -> W2T[n][k]
    if (u < HID*HC1){
      int n = u >> 8, k = u & 255;
      w2t[u] = f2b(w2[(size_t)k*HID + n]);
    }
  }
}

// ---------------- GEMM1 (bf16 MFMA, fused x->bf16): x[M,128] @ W1 -> h1b[M,256] ------
__global__ __launch_bounds__(256) void k_gemm1b(const float* __restrict__ x,
    const unsigned short* __restrict__ w1t, unsigned short* __restrict__ h1b, int M){
  __shared__ unsigned short As[64][136];  // [m][k], +8 pad (2-way aliasing free)
  __shared__ unsigned short Bs[64][136];  // [n][k]
  int tid = threadIdx.x;
  int rowbase = blockIdx.x * 64;
  int colbase = blockIdx.y * 64;
  #pragma unroll
  for (int j = 0; j < 8; ++j){            // A: 64x128 fp32 -> bf16
    int idx = (tid + 256*j) * 4;
    int r = idx >> 7, c = idx & 127;
    int row = rowbase + r;
    float4 v = make_float4(0.f,0.f,0.f,0.f);
    if (row < M) v = *(const float4*)(x + (size_t)row*F_IN + c);
    unsigned short q[4] = { f2b(v.x), f2b(v.y), f2b(v.z), f2b(v.w) };
    *(uint2*)&As[r][c] = *(const uint2*)q;
  }
  #pragma unroll
  for (int j = 0; j < 4; ++j){            // B: 64x128 bf16
    int idx = (tid + 256*j) * 8;
    int r = idx >> 7, c = idx & 127;
    *(uint4*)&Bs[r][c] = *(const uint4*)(w1t + (size_t)(colbase + r)*F_IN + c);
  }
  __syncthreads();
  int wv = tid >> 6, lane = tid & 63;
  int m0 = (wv >> 1) * 32, n0 = (wv & 1) * 32;
  int lr = lane & 15, lq = lane >> 4;
  f32x4 acc[2][2] = {};
  #pragma unroll
  for (int k0 = 0; k0 < F_IN; k0 += 32){
    bf16x8 a0 = *(const bf16x8*)&As[m0 + lr][k0 + lq*8];
    bf16x8 a1 = *(const bf16x8*)&As[m0 + 16 + lr][k0 + lq*8];
    bf16x8 b0 = *(const bf16x8*)&Bs[n0 + lr][k0 + lq*8];
    bf16x8 b1 = *(const bf16x8*)&Bs[n0 + 16 + lr][k0 + lq*8];
    acc[0][0] = __builtin_amdgcn_mfma_f32_16x16x32_bf16(a0, b0, acc[0][0], 0, 0, 0);
    acc[0][1] = __builtin_amdgcn_mfma_f32_16x16x32_bf16(a0, b1, acc[0][1], 0, 0, 0);
    acc[1][0] = __builtin_amdgcn_mfma_f32_16x16x32_bf16(a1, b0, acc[1][0], 0, 0, 0);
    acc[1][1] = __builtin_amdgcn_mfma_f32_16x16x32_bf16(a1, b1, acc[1][1], 0, 0, 0);
  }
  #pragma unroll
  for (int i = 0; i < 2; ++i){
    #pragma unroll
    for (int j = 0; j < 2; ++j){
      #pragma unroll
      for (int r = 0; r < 4; ++r){
        int row = rowbase + m0 + i*16 + lq*4 + r;
        int col = colbase + n0 + j*16 + lr;
        if (row < M) h1b[(size_t)row*HC1 + col] = f2b(acc[i][j][r]);
      }
    }
  }
}

// ------ GEMM2 (bf16 MFMA, no LDS) + fused alpha2: h2b @ W2T -> g2b bf16, asrc2/adst2 --
__global__ __launch_bounds__(256) void k_gemm2b(const unsigned short* __restrict__ h2b,
    const unsigned short* __restrict__ w2t, unsigned short* __restrict__ g2b,
    const float* __restrict__ as2w, const float* __restrict__ ad2w,
    float* __restrict__ asrc2, float* __restrict__ adst2, int M){
  int tid = threadIdx.x;
  int wv = tid >> 6, lane = tid & 63;
  int lr = lane & 15, lq = lane >> 4;
  int m0 = blockIdx.x*64 + wv*16;
  int arow = m0 + lr;
  bool ok = arow < M;
  const unsigned short* ap  = h2b + (size_t)arow*HC1 + lq*8;
  const unsigned short* b0p = w2t + (size_t)lr*HC1 + lq*8;
  const unsigned short* b1p = w2t + (size_t)(16 + lr)*HC1 + lq*8;
  f32x4 acc0 = {}, acc1 = {};
  #pragma unroll
  for (int k0 = 0; k0 < HC1; k0 += 32){
    bf16x8 a  = ok ? *(const bf16x8*)(ap + k0) : (bf16x8){0,0,0,0,0,0,0,0};
    bf16x8 b0 = *(const bf16x8*)(b0p + k0);
    bf16x8 b1 = *(const bf16x8*)(b1p + k0);
    acc0 = __builtin_amdgcn_mfma_f32_16x16x32_bf16(a, b0, acc0, 0, 0, 0);
    acc1 = __builtin_amdgcn_mfma_f32_16x16x32_bf16(a, b1, acc1, 0, 0, 0);
  }
  #pragma unroll
  for (int r = 0; r < 4; ++r){
    int orow = m0 + lq*4 + r;
    if (orow < M){
      g2b[(size_t)orow*HID + lr]      = f2b(acc0[r]);
      g2b[(size_t)orow*HID + 16 + lr] = f2b(acc1[r]);
    }
  }
  // fused alpha2: per-row dot with a_src2/a_dst2 (32 cols spread over 16 lanes x 2 accs)
  float asl = as2w[lr], ash = as2w[16 + lr];
  float adl = ad2w[lr], adh = ad2w[16 + lr];
  float ps[4], pd[4];
  #pragma unroll
  for (int r = 0; r < 4; ++r){
    ps[r] = acc0[r]*asl + acc1[r]*ash;
    pd[r] = acc0[r]*adl + acc1[r]*adh;
  }
  #pragma unroll
  for (int mask = 1; mask <= 8; mask <<= 1){
    #pragma unroll
    for (int r = 0; r < 4; ++r){
      ps[r] += __shfl_xor(ps[r], mask, 64);
      pd[r] += __shfl_xor(pd[r], mask, 64);
    }
  }
  if (lr == 0){
    #pragma unroll
    for (int r = 0; r < 4; ++r){
      int orow = m0 + lq*4 + r;
      if (orow < M){ asrc2[orow] = ps[r]; adst2[orow] = pd[r]; }
    }
  }
}

// ---------------- per-node alpha dots, layer 1 ----------------
__global__ void k_alpha1(const unsigned short* __restrict__ h1b, const float* __restrict__ a_src,
                         const float* __restrict__ a_dst, float* __restrict__ os,
                         float* __restrict__ od, int NH){
  int t = blockIdx.x*blockDim.x + threadIdx.x;
  if (t >= NH) return;
  int h = t & 7;
  const float4* sp = (const float4*)(a_src + h*HID);
  const float4* dp = (const float4*)(a_dst + h*HID);
  float ss = 0.f, dd = 0.f;
  #pragma unroll
  for (int j = 0; j < 4; ++j){
    uint4 u = *(const uint4*)(h1b + (size_t)t*HID + j*8);
    float v0 = blo(u.x), v1 = bhi(u.x);
    float v2 = blo(u.y), v3 = bhi(u.y);
    float v4 = blo(u.z), v5 = bhi(u.z);
    float v6 = blo(u.w), v7 = bhi(u.w);
    float4 s0 = sp[2*j], s1 = sp[2*j+1];
    float4 d0 = dp[2*j], d1 = dp[2*j+1];
    ss += v0*s0.x + v1*s0.y + v2*s0.z + v3*s0.w + v4*s1.x + v5*s1.y + v6*s1.z + v7*s1.w;
    dd += v0*d0.x + v1*d0.y + v2*d0.z + v3*d0.w + v4*d1.x + v5*d1.y + v6*d1.z + v7*d1.w;
  }
  os[t] = ss; od[t] = dd;
}

// ---------------- layer-1 aggregation: wave/node, unroll x4, bf16 ----------------
__global__ __launch_bounds__(256) void k_agg1(const unsigned short* __restrict__ h1b,
    const float* __restrict__ as1, const float* __restrict__ ad1,
    const int* __restrict__ offs, const int* __restrict__ deg,
    const int* __restrict__ csr,
    const float* __restrict__ b1, unsigned short* __restrict__ h2b, int N){
  int w = (blockIdx.x*blockDim.x + threadIdx.x) >> 6;
  if (w >= N) return;
  int lane = threadIdx.x & 63;
  int c0 = lane << 2;        // col 0..252
  int h = lane >> 3;         // head 0..7
  float adv = ad1[w*HEADS + h];
  float p0 = __expf(lrelu(as1[w*HEADS + h] + adv));   // self-loop
  float l = p0;
  uint2 sv = *(const uint2*)(h1b + (size_t)w*HC1 + c0);
  float4 acc = make_float4(p0*blo(sv.x), p0*bhi(sv.x), p0*blo(sv.y), p0*bhi(sv.y));
  int i = offs[w];
  int e1 = i + deg[w];
  for (; i + 4 <= e1; i += 4){
    int sA = csr[i], sB = csr[i+1], sC = csr[i+2], sD = csr[i+3];
    float aA = as1[sA*HEADS + h], aB = as1[sB*HEADS + h];
    float aC = as1[sC*HEADS + h], aD = as1[sD*HEADS + h];
    uint2 uA = *(const uint2*)(h1b + (size_t)sA*HC1 + c0);
    uint2 uB = *(const uint2*)(h1b + (size_t)sB*HC1 + c0);
    uint2 uC = *(const uint2*)(h1b + (size_t)sC*HC1 + c0);
    uint2 uD = *(const uint2*)(h1b + (size_t)sD*HC1 + c0);
    float pA = __expf(lrelu(aA + adv)), pB = __expf(lrelu(aB + adv));
    float pC = __expf(lrelu(aC + adv)), pD = __expf(lrelu(aD + adv));
    l += (pA + pB) + (pC + pD);
    acc.x += pA*blo(uA.x) + pB*blo(uB.x) + pC*blo(uC.x) + pD*blo(uD.x);
    acc.y += pA*bhi(uA.x) + pB*bhi(uB.x) + pC*bhi(uC.x) + pD*bhi(uD.x);
    acc.z += pA*blo(uA.y) + pB*blo(uB.y) + pC*blo(uC.y) + pD*blo(uD.y);
    acc.w += pA*bhi(uA.y) + pB*bhi(uB.y) + pC*bhi(uC.y) + pD*bhi(uD.y);
  }
  for (; i < e1; ++i){
    int s = csr[i];
    float p = __expf(lrelu(as1[s*HEADS + h] + adv));
    uint2 u = *(const uint2*)(h1b + (size_t)s*HC1 + c0);
    l += p;
    acc.x += p*blo(u.x); acc.y += p*bhi(u.x);
    acc.z += p*blo(u.y); acc.w += p*bhi(u.y);
  }
  float rl = 1.f / l;
  float4 bb = *(const float4*)(b1 + c0);
  float4 o;
  o.x = acc.x*rl + bb.x; o.y = acc.y*rl + bb.y;
  o.z = acc.z*rl + bb.z; o.w = acc.w*rl + bb.w;
  o.x = o.x > 0.f ? o.x : __expf(o.x) - 1.f;
  o.y = o.y > 0.f ? o.y : __expf(o.y) - 1.f;
  o.z = o.z > 0.f ? o.z : __expf(o.z) - 1.f;
  o.w = o.w > 0.f ? o.w : __expf(o.w) - 1.f;
  unsigned lo = (unsigned)f2b(o.x) | ((unsigned)f2b(o.y) << 16);
  unsigned hi = (unsigned)f2b(o.z) | ((unsigned)f2b(o.w) << 16);
  *(uint2*)(h2b + (size_t)w*HC1 + c0) = make_uint2(lo, hi);
}

// ---------------- layer-2 aggregation: wave/node, 8 edge-groups, bf16 gather ----------
__global__ __launch_bounds__(256) void k_agg2(const unsigned short* __restrict__ g2b,
    const float* __restrict__ as2, const float* __restrict__ ad2,
    const int* __restrict__ offs, const int* __restrict__ deg,
    const int* __restrict__ csr,
    const float* __restrict__ b2, float* __restrict__ out, int N){
  int w = (blockIdx.x*blockDim.x + threadIdx.x) >> 6;
  if (w >= N) return;
  int lane = threadIdx.x & 63;
  int g = lane >> 3;          // edge group 0..7
  int c0 = (lane & 7) << 2;   // col 0..28
  float adv = ad2[w];
  float l = 0.f;
  float4 acc = make_float4(0.f,0.f,0.f,0.f);
  if (g == 0){
    float p0 = __expf(lrelu(as2[w] + adv));
    l = p0;
    uint2 sv = *(const uint2*)(g2b + (size_t)w*HID + c0);
    acc = make_float4(p0*blo(sv.x), p0*bhi(sv.x), p0*blo(sv.y), p0*bhi(sv.y));
  }
  int s0 = offs[w];
  int e1 = s0 + deg[w];
  for (int i = s0 + g; i < e1; i += 8){
    int s = csr[i];
    float p = __expf(lrelu(as2[s] + adv));
    uint2 u = *(const uint2*)(g2b + (size_t)s*HID + c0);
    l += p;
    acc.x += p*blo(u.x); acc.y += p*bhi(u.x);
    acc.z += p*blo(u.y); acc.w += p*bhi(u.y);
  }
  #pragma unroll
  for (int mask = 8; mask <= 32; mask <<= 1){
    l     += __shfl_xor(l, mask, 64);
    acc.x += __shfl_xor(acc.x, mask, 64);
    acc.y += __shfl_xor(acc.y, mask, 64);
    acc.z += __shfl_xor(acc.z, mask, 64);
    acc.w += __shfl_xor(acc.w, mask, 64);
  }
  if (g == 0){
    float rl = 1.f/l;
    float4 bb = *(const float4*)(b2 + c0);
    *(float4*)(out + (size_t)w*HID + c0) =
      make_float4(acc.x*rl + bb.x, acc.y*rl + bb.y, acc.z*rl + bb.z, acc.w*rl + bb.w);
  }
}

extern "C" void kernel_launch(void* const* d_in, const int* in_sizes, int n_in,
                              void* d_out, int out_size, void* d_ws, size_t ws_size,
                              hipStream_t stream){
  const float* x    = (const float*)d_in[0];
  const int*   ei   = (const int*)d_in[1];
  const float* W1   = (const float*)d_in[2];
  const float* as1w = (const float*)d_in[3];
  const float* ad1w = (const float*)d_in[4];
  const float* b1   = (const float*)d_in[5];
  const float* W2   = (const float*)d_in[6];
  const float* as2w = (const float*)d_in[7];
  const float* ad2w = (const float*)d_in[8];
  const float* b2   = (const float*)d_in[9];
  float* out = (float*)d_out;

  const int N = in_sizes[0] / F_IN;      // 50000
  const int E = in_sizes[1] / 2;         // 800000
  const int* srcA = ei;
  const int* dstA = ei + E;

  float* asrc1 = (float*)d_ws;                     // N*8
  float* adst1 = asrc1 + (size_t)N*HEADS;          // N*8
  float* asrc2 = adst1 + (size_t)N*HEADS;          // N
  float* adst2 = asrc2 + N;                        // N
  unsigned short* w1tb = (unsigned short*)(adst2 + N);   // 256*128
  unsigned short* w2tb = w1tb + (size_t)HC1*F_IN;        // 32*256
  unsigned short* h1b  = w2tb + (size_t)HID*HC1;         // N*256
  unsigned short* h2b  = h1b  + (size_t)N*HC1;           // N*256
  unsigned short* g2b  = h2b  + (size_t)N*HC1;           // N*32
  int* deg  = (int*)(g2b + (size_t)N*HID);
  int* cur  = deg  + N;
  int* gcur = cur  + N;       // 1 int
  int* offs = gcur + 1;       // N
  int* csr  = offs + N;       // E

  // zero deg, cur, gcur (contiguous)
  hipMemsetAsync(deg, 0, ((size_t)2*N + 1)*sizeof(int), stream);

  k_deg    <<<(E+255)/256, 256, 0, stream>>>(dstA, deg, E);
  k_alloc  <<<(N+255)/256, 256, 0, stream>>>(deg, offs, gcur, N);
  k_scatter<<<(E+255)/256, 256, 0, stream>>>(srcA, dstA, offs, cur, csr, E);

  k_cvt_w  <<<(HC1*F_IN + HID*HC1 + 255)/256, 256, 0, stream>>>(W1, W2, w1tb, w2tb);

  dim3 g1((N + 63)/64, HC1/64);
  k_gemm1b<<<g1, 256, 0, stream>>>(x, w1tb, h1b, N);
  k_alpha1<<<(N*HEADS + 255)/256, 256, 0, stream>>>(h1b, as1w, ad1w, asrc1, adst1, N*HEADS);
  k_agg1  <<<(N + 3)/4, 256, 0, stream>>>(h1b, asrc1, adst1, offs, deg, csr, b1, h2b, N);

  k_gemm2b<<<(N + 63)/64, 256, 0, stream>>>(h2b, w2tb, g2b, as2w, ad2w, asrc2, adst2, N);
  k_agg2  <<<(N + 3)/4, 256, 0, stream>>>(g2b, asrc2, adst2, offs, deg, csr, b2, out, N);
}